// Round 3
// baseline (202.297 us; speedup 1.0000x reference)
//
#include <hip/hip_runtime.h>

#define B_SZ 8
#define T_LEN 4096
#define N_DIM 256
#define H_DIM 512
#define NC 32
#define CL 128
#define ROWS (B_SZ * T_LEN)

typedef __attribute__((ext_vector_type(4))) float f32x4;
typedef __attribute__((ext_vector_type(8))) short bf16x8;

static __device__ __forceinline__ unsigned short f2bf(float f) {
    unsigned int u = __float_as_uint(f);
    unsigned int r = (u + 0x7FFFu + ((u >> 16) & 1u)) >> 16;
    return (unsigned short)r;
}
static __device__ __forceinline__ float bf2f(unsigned short s) {
    return __uint_as_float(((unsigned int)s) << 16);
}

static __device__ __forceinline__ void lam_of(const float* __restrict__ nu,
                                              const float* __restrict__ theta,
                                              int h, float& lre, float& lim) {
    float r = __expf(-__expf(nu[h]));
    float th = theta[h];
    lre = r * __cosf(th);
    lim = r * __sinf(th);
}

// ---------- conversion kernels ----------
__global__ __launch_bounds__(256) void conv_x(const float4* __restrict__ x, ushort4* __restrict__ xb) {
    int id = blockIdx.x * 256 + threadIdx.x;
    float4 v = x[id];
    ushort4 o;
    o.x = f2bf(v.x); o.y = f2bf(v.y); o.z = f2bf(v.z); o.w = f2bf(v.w);
    xb[id] = o;
}

// BT1[n][k] (1024 x 256): n=2h -> Bre[k][h], n=2h+1 -> Bim[k][h]
__global__ __launch_bounds__(256) void conv_Bt(const float* __restrict__ Bre,
                                               const float* __restrict__ Bim,
                                               unsigned short* __restrict__ BT1) {
    int id = blockIdx.x * 256 + threadIdx.x;           // id = k*512 + h
    int k = id >> 9, h = id & 511;
    BT1[(long)(2 * h) * 256 + k]     = f2bf(Bre[id]);
    BT1[(long)(2 * h + 1) * 256 + k] = f2bf(Bim[id]);
}

// CT[n][k] (256 x 1024): k=2h -> Cre[h][n], k=2h+1 -> -Cim[h][n]
__global__ __launch_bounds__(256) void conv_Ct(const float* __restrict__ Cre,
                                               const float* __restrict__ Cim,
                                               unsigned short* __restrict__ CT) {
    int id = blockIdx.x * 256 + threadIdx.x;           // id = h*256 + nn
    int h = id >> 8, nn = id & 255;
    CT[(long)nn * 1024 + 2 * h]     = f2bf(Cre[id]);
    CT[(long)nn * 1024 + 2 * h + 1] = f2bf(-Cim[id]);
}

// ---------- direct-register MFMA GEMM: out = A(MxK) @ Bt(NxK)^T ----------
// R3: no LDS, no barriers, no staging.  Each 128x128 block = 4 waves in a
// 2x2 grid, each wave owns a 64x64 output and loads its A/B fragments
// DIRECTLY global->VGPR.  Rationale: B panels are 0.5 MB (L2-resident), and
// within a block the two waves sharing an A-frag (resp. B-frag) read
// identical addresses -> L1 dedupes, so unique L2 traffic equals the staged
// version.  K is a template constant: every fragment address is per-lane
// base + compile-time immediate, so the K-loop is pure
// {global_load_dwordx4 offset:imm} + MFMA with zero per-iter address math
// and zero cross-wave dependencies.  Latency hidden by ILP (unrolled load
// hoisting) x TLP (independent waves, no lockstep).
// MODE 0: K1 epilogue (scale by gamma[col/2], store bf16)
// MODE 1: K3 epilogue (add D[col]*u[row][col], store f32); u from e1b (bf16) if non-null else e1 (f32)
template <int MODE, int KC>
__global__ __launch_bounds__(256) void gemm_direct(const unsigned short* __restrict__ A,
                                                   const unsigned short* __restrict__ Bt,
                                                   int N,
                                                   const float* __restrict__ e0,
                                                   const float* __restrict__ e1,
                                                   const unsigned short* __restrict__ e1b,
                                                   void* __restrict__ out) {
    const int tid = threadIdx.x;
    const int lane = tid & 63;
    const int wave = tid >> 6;
    const int wr = wave >> 1, wc = wave & 1;

    // XCD-aware swizzle (grid % 8 == 0 for both instantiations)
    const int nwg = (int)gridDim.x;
    const int cpx = nwg >> 3;
    const int bid = (int)blockIdx.x;
    const int tile = (bid & 7) * cpx + (bid >> 3);

    const int nTilesN = N / 128;
    const long tileM = (long)(tile / nTilesN) * 128;
    const long tileN = (long)(tile % nTilesN) * 128;

    // fragment base: lane l supplies A[row = l&15][k = (l>>4)*8 + j]
    const int fr = lane & 15;
    const int fs = lane >> 4;
    const unsigned short* ap = A + (tileM + wr * 64 + fr) * (long)KC + fs * 8;
    const unsigned short* bp = Bt + (tileN + wc * 64 + fr) * (long)KC + fs * 8;

    f32x4 acc[4][4] = {};

    constexpr int NT = KC / 32;
#if 1
#pragma unroll (KC == 256 ? 8 : 8)
#endif
    for (int t = 0; t < NT; ++t) {
        bf16x8 af[4], bfr[4];
#pragma unroll
        for (int m = 0; m < 4; ++m)
            af[m] = *(const bf16x8*)(ap + (long)m * 16 * KC + t * 32);
#pragma unroll
        for (int n = 0; n < 4; ++n)
            bfr[n] = *(const bf16x8*)(bp + (long)n * 16 * KC + t * 32);
#pragma unroll
        for (int m = 0; m < 4; ++m)
#pragma unroll
            for (int n = 0; n < 4; ++n)
                acc[m][n] = __builtin_amdgcn_mfma_f32_16x16x32_bf16(af[m], bfr[n], acc[m][n], 0, 0, 0);
    }

    if constexpr (MODE == 0) {
        unsigned short* o = (unsigned short*)out;
#pragma unroll
        for (int n = 0; n < 4; ++n) {
            const int gcol = (int)tileN + wc * 64 + n * 16 + fr;
            const float g = __expf(e0[gcol >> 1]);
#pragma unroll
            for (int m = 0; m < 4; ++m) {
                const long grow0 = tileM + wr * 64 + m * 16 + (fs << 2);
#pragma unroll
                for (int r = 0; r < 4; ++r)
                    o[(grow0 + r) * N + gcol] = f2bf(acc[m][n][r] * g);
            }
        }
    } else {
        float* o = (float*)out;
#pragma unroll
        for (int n = 0; n < 4; ++n) {
            const int gcol = (int)tileN + wc * 64 + n * 16 + fr;
            const float dv = e0[gcol];
#pragma unroll
            for (int m = 0; m < 4; ++m) {
                const long grow0 = tileM + wr * 64 + m * 16 + (fs << 2);
#pragma unroll
                for (int r = 0; r < 4; ++r) {
                    const long idx = (grow0 + r) * N + gcol;
                    const float uv = e1b ? bf2f(e1b[idx]) : e1[idx];
                    o[idx] = acc[m][n][r] + dv * uv;
                }
            }
        }
    }
}

// ---------- scan: sums-first, then fused local-scan-from-carry ----------
// thread handles 2 complex h's (ushort4 = 8B loads, 512B/wave coalesced)

// k2s: read-only chunk sums. sums[(b*NC+c)*256+hp] = (re0,im0,re1,im1)
__global__ __launch_bounds__(256) void k2s_sums(const ushort4* __restrict__ xs4,
                                                float4* __restrict__ sums,
                                                const float* __restrict__ nu,
                                                const float* __restrict__ theta) {
    const int gid = blockIdx.x * 256 + threadIdx.x;   // 8*32*256
    const int hp = gid & 255;
    const int c = (gid >> 8) & (NC - 1);
    const int b = gid >> 13;
    float lre0, lim0, lre1, lim1;
    lam_of(nu, theta, 2 * hp, lre0, lim0);
    lam_of(nu, theta, 2 * hp + 1, lre1, lim1);
    long base = ((long)b * T_LEN + (long)c * CL) * 256 + hp;
    float a0r = 0.f, a0i = 0.f, a1r = 0.f, a1i = 0.f;
#pragma unroll 4
    for (int i = 0; i < CL; ++i) {
        ushort4 v = xs4[base + (long)i * 256];
        float u0r = bf2f(v.x), u0i = bf2f(v.y), u1r = bf2f(v.z), u1i = bf2f(v.w);
        float n0r = fmaf(lre0, a0r, fmaf(-lim0, a0i, u0r));
        float n0i = fmaf(lre0, a0i, fmaf(lim0, a0r, u0i));
        float n1r = fmaf(lre1, a1r, fmaf(-lim1, a1i, u1r));
        float n1i = fmaf(lre1, a1i, fmaf(lim1, a1r, u1i));
        a0r = n0r; a0i = n0i; a1r = n1r; a1i = n1i;
    }
    sums[((long)b * NC + c) * 256 + hp] = make_float4(a0r, a0i, a1r, a1i);
}

// k2b: exclusive scan over chunk sums -> carry (same float4-per-hp layout)
__global__ __launch_bounds__(256) void k2b_carry(const float4* __restrict__ sums,
                                                 float4* __restrict__ carry,
                                                 const float* __restrict__ nu,
                                                 const float* __restrict__ theta) {
    const int gid = blockIdx.x * 256 + threadIdx.x;   // 8*256
    const int hp = gid & 255;
    const int b = gid >> 8;
    float lre0, lim0, lre1, lim1;
    lam_of(nu, theta, 2 * hp, lre0, lim0);
    lam_of(nu, theta, 2 * hp + 1, lre1, lim1);
    // lam^CL via 7 complex squarings (CL = 128 = 2^7)
    float p0r = lre0, p0i = lim0, p1r = lre1, p1i = lim1;
#pragma unroll
    for (int i = 0; i < 7; ++i) {
        float t0 = p0r * p0r - p0i * p0i; p0i = 2.f * p0r * p0i; p0r = t0;
        float t1 = p1r * p1r - p1i * p1i; p1i = 2.f * p1r * p1i; p1r = t1;
    }
    float c0r = 0.f, c0i = 0.f, c1r = 0.f, c1i = 0.f;
    for (int c = 0; c < NC; ++c) {
        long idx = ((long)b * NC + c) * 256 + hp;
        carry[idx] = make_float4(c0r, c0i, c1r, c1i);
        float4 s = sums[idx];
        float t0 = fmaf(p0r, c0r, fmaf(-p0i, c0i, s.x));
        c0i = fmaf(p0r, c0i, fmaf(p0i, c0r, s.y));
        c0r = t0;
        float t1 = fmaf(p1r, c1r, fmaf(-p1i, c1i, s.z));
        c1i = fmaf(p1r, c1i, fmaf(p1i, c1r, s.w));
        c1r = t1;
    }
}

// k2ac: fused local scan starting from carry -> final xs (one R+W pass, f32 state throughout)
__global__ __launch_bounds__(256) void k2ac_scan(ushort4* __restrict__ xs4,
                                                 const float4* __restrict__ carry,
                                                 const float* __restrict__ nu,
                                                 const float* __restrict__ theta) {
    const int gid = blockIdx.x * 256 + threadIdx.x;   // 8*32*256
    const int hp = gid & 255;
    const int c = (gid >> 8) & (NC - 1);
    const int b = gid >> 13;
    float lre0, lim0, lre1, lim1;
    lam_of(nu, theta, 2 * hp, lre0, lim0);
    lam_of(nu, theta, 2 * hp + 1, lre1, lim1);
    float4 cr = carry[((long)b * NC + c) * 256 + hp];
    float a0r = cr.x, a0i = cr.y, a1r = cr.z, a1i = cr.w;
    long base = ((long)b * T_LEN + (long)c * CL) * 256 + hp;
#pragma unroll 4
    for (int i = 0; i < CL; ++i) {
        ushort4 v = xs4[base + (long)i * 256];
        float u0r = bf2f(v.x), u0i = bf2f(v.y), u1r = bf2f(v.z), u1i = bf2f(v.w);
        float n0r = fmaf(lre0, a0r, fmaf(-lim0, a0i, u0r));
        float n0i = fmaf(lre0, a0i, fmaf(lim0, a0r, u0i));
        float n1r = fmaf(lre1, a1r, fmaf(-lim1, a1i, u1r));
        float n1i = fmaf(lre1, a1i, fmaf(lim1, a1r, u1i));
        a0r = n0r; a0i = n0i; a1r = n1r; a1i = n1i;
        ushort4 o;
        o.x = f2bf(a0r); o.y = f2bf(a0i); o.z = f2bf(a1r); o.w = f2bf(a1i);
        xs4[base + (long)i * 256] = o;
    }
}

extern "C" void kernel_launch(void* const* d_in, const int* in_sizes, int n_in,
                              void* d_out, int out_size, void* d_ws, size_t ws_size,
                              hipStream_t stream) {
    const float* x         = (const float*)d_in[0];
    const float* Bre       = (const float*)d_in[1];
    const float* Bim       = (const float*)d_in[2];
    const float* Cre       = (const float*)d_in[3];
    const float* Cim       = (const float*)d_in[4];
    const float* Dv        = (const float*)d_in[5];
    const float* nu        = (const float*)d_in[6];
    const float* theta     = (const float*)d_in[7];
    const float* gamma_log = (const float*)d_in[8];
    float* y = (float*)d_out;

    // ws layout:
    //   [0, 64MB)      xs (bf16 interleaved re,im)
    //   [64MB, 66MB)   region A: BT1 (0.5MB) -> sums (1MB) -> CT (0.5MB)
    //   [66MB, 68MB)   region B: carry (1MB)
    //   [68MB, 84MB)   xb (bf16 x) IF ws_size permits, else xb lives in d_out
    const size_t XS_BYTES  = (size_t)ROWS * H_DIM * 4;
    const size_t REG_BYTES = 2u * 1024 * 1024;
    const size_t XB_BYTES  = (size_t)ROWS * N_DIM * 2;
    unsigned short* xs_us = (unsigned short*)d_ws;
    ushort4* xs4   = (ushort4*)d_ws;
    char* regionA  = (char*)d_ws + XS_BYTES;
    char* regionB  = regionA + REG_BYTES;
    unsigned short* BT1 = (unsigned short*)regionA;
    float4*  sums  = (float4*)regionA;
    unsigned short* CT  = (unsigned short*)regionA;
    float4*  carry = (float4*)regionB;

    const bool xb_in_ws = ws_size >= XS_BYTES + 2 * REG_BYTES + XB_BYTES;
    unsigned short* xb = xb_in_ws ? (unsigned short*)(regionB + REG_BYTES)
                                  : (unsigned short*)d_out;

    conv_x<<<ROWS * N_DIM / 4 / 256, 256, 0, stream>>>((const float4*)x, (ushort4*)xb);
    conv_Bt<<<(N_DIM * H_DIM) / 256, 256, 0, stream>>>(Bre, Bim, BT1);

    // K1: xs = gamma * (u @ Bint)   M=32768 N=1024 K=256   (2048 blocks, no LDS)
    gemm_direct<0, 256><<<(ROWS / 128) * (1024 / 128), 256, 0, stream>>>(
        xb, BT1, 1024, gamma_log, nullptr, nullptr, xs_us);
    // scan: sums-first (sums overwrites BT1 region; K1 complete by stream order)
    k2s_sums<<<(B_SZ * NC * 256) / 256, 256, 0, stream>>>(xs4, sums, nu, theta);
    k2b_carry<<<(B_SZ * 256) / 256, 256, 0, stream>>>(sums, carry, nu, theta);
    k2ac_scan<<<(B_SZ * NC * 256) / 256, 256, 0, stream>>>(xs4, carry, nu, theta);

    // CT overwrites sums region (dead after k2b)
    conv_Ct<<<(H_DIM * N_DIM) / 256, 256, 0, stream>>>(Cre, Cim, CT);

    // K3: y = Re(xs @ C) + D*u      M=32768 N=256 K=1024   (512 blocks, no LDS)
    gemm_direct<1, 1024><<<(ROWS / 128) * (256 / 128), 256, 0, stream>>>(
        xs_us, CT, 256, Dv, x, xb_in_ws ? xb : nullptr, y);
}

// Round 4
// 129.290 us; speedup vs baseline: 1.5647x; 1.5647x over previous
//
#include <hip/hip_runtime.h>

#define B_SZ 8
#define T_LEN 4096
#define N_DIM 256
#define H_DIM 512
#define NC 32
#define CL 128
#define ROWS (B_SZ * T_LEN)

#define BM 128
#define BN 128
#define BKg 32

typedef __attribute__((ext_vector_type(4))) float f32x4;
typedef __attribute__((ext_vector_type(8))) short bf16x8;

static __device__ __forceinline__ unsigned short f2bf(float f) {
    unsigned int u = __float_as_uint(f);
    unsigned int r = (u + 0x7FFFu + ((u >> 16) & 1u)) >> 16;
    return (unsigned short)r;
}
static __device__ __forceinline__ float bf2f(unsigned short s) {
    return __uint_as_float(((unsigned int)s) << 16);
}

static __device__ __forceinline__ void lam_of(const float* __restrict__ nu,
                                              const float* __restrict__ theta,
                                              int h, float& lre, float& lim) {
    float r = __expf(-__expf(nu[h]));
    float th = theta[h];
    lre = r * __cosf(th);
    lim = r * __sinf(th);
}

// ---------- conversion kernels ----------
__global__ __launch_bounds__(256) void conv_x(const float4* __restrict__ x, ushort4* __restrict__ xb) {
    int id = blockIdx.x * 256 + threadIdx.x;
    float4 v = x[id];
    ushort4 o;
    o.x = f2bf(v.x); o.y = f2bf(v.y); o.z = f2bf(v.z); o.w = f2bf(v.w);
    xb[id] = o;
}

// BT1[n][k] (1024 x 256): n=2h -> Bre[k][h], n=2h+1 -> Bim[k][h]
__global__ __launch_bounds__(256) void conv_Bt(const float* __restrict__ Bre,
                                               const float* __restrict__ Bim,
                                               unsigned short* __restrict__ BT1) {
    int id = blockIdx.x * 256 + threadIdx.x;           // id = k*512 + h
    int k = id >> 9, h = id & 511;
    BT1[(long)(2 * h) * 256 + k]     = f2bf(Bre[id]);
    BT1[(long)(2 * h + 1) * 256 + k] = f2bf(Bim[id]);
}

// CT[n][k] (256 x 1024): k=2h -> Cre[h][n], k=2h+1 -> -Cim[h][n]
__global__ __launch_bounds__(256) void conv_Ct(const float* __restrict__ Cre,
                                               const float* __restrict__ Cim,
                                               unsigned short* __restrict__ CT) {
    int id = blockIdx.x * 256 + threadIdx.x;           // id = h*256 + nn
    int h = id >> 8, nn = id & 255;
    CT[(long)nn * 1024 + 2 * h]     = f2bf(Cre[id]);
    CT[(long)nn * 1024 + 2 * h + 1] = f2bf(-Cim[id]);
}

// ---------- MFMA GEMM: out = A(MxK) @ Bt(NxK)^T, bf16 in, f32 acc ----------
// K-loop: R1 structure (verified best): 3 LDS buffers, depth-2 counted-vmcnt
// pipeline, RAW s_barrier (no vmcnt drain), write-side XOR swizzle via
// pre-permuted global source + matching read-side XOR (0 bank conflicts).
// R4 change: SWAPPED MFMA OPERANDS -> mfma(bfr, af, acc) computes the
// transposed 16x16 tile, so each lane holds (row = lane&15, cols =
// (lane>>4)*4 + r) = 4 CONSECUTIVE output columns of ONE row.  Epilogue
// becomes 16 vector stores/thread (ushort4 / float4), fully line-coalesced
// (16 rows x 64B per instruction), replacing 64 scattered scalar stores --
// which the R0-R3 invariant (~54us regardless of K-loop shape) identified
// as the real bottleneck.
// MODE 0: K1 epilogue (scale by gamma[col/2], store bf16)
// MODE 1: K3 epilogue (add D[col]*u[row][col], store f32); u from e1b (bf16) if non-null else e1 (f32)
template <int MODE>
__global__ __launch_bounds__(256) void gemm_mfma(const unsigned short* __restrict__ A,
                                                 const unsigned short* __restrict__ Bt,
                                                 int M, int N, int K,
                                                 const float* __restrict__ e0,
                                                 const float* __restrict__ e1,
                                                 const unsigned short* __restrict__ e1b,
                                                 void* __restrict__ out) {
    __shared__ unsigned short As[3][BM * BKg];   // 3 x 8 KB
    __shared__ unsigned short Bs[3][BN * BKg];   // 3 x 8 KB
    const int tid = threadIdx.x;
    const int lane = tid & 63;
    const int wave = tid >> 6;
    const int wr = wave >> 1, wc = wave & 1;

    // XCD-aware swizzle (grid % 8 == 0 for both instantiations)
    const int nwg = (int)gridDim.x;
    const int cpx = nwg >> 3;
    const int bid = (int)blockIdx.x;
    const int tile = (bid & 7) * cpx + (bid >> 3);

    const int nTilesN = N / BN;
    const long tileM = (long)(tile / nTilesN) * BM;
    const long tileN = (long)(tile % nTilesN) * BN;

    // staging geometry (per-lane constants).  LDS row r = c*16 + (lane>>2),
    // LDS slot = lane&3 (16B units).  Source k-segment = slot ^ ((r>>1)&3),
    // and (r>>1)&3 == (lane>>3)&3 here.
    const int rsub = lane >> 2;
    const int sg = 8 * ((lane & 3) ^ ((lane >> 3) & 3));    // swizzled k-offset (ushorts)
    const unsigned short* Abase = A + tileM * (long)K + sg;
    const unsigned short* Bbase = Bt + tileN * (long)K + sg;

    auto stage = [&](int buf, int k0) {
#pragma unroll
        for (int cc = 0; cc < 2; ++cc) {
            const int c = wave + cc * 4;
            const int row = c * 16 + rsub;
            const unsigned short* ga = Abase + (long)row * K + k0;
            __builtin_amdgcn_global_load_lds((const __attribute__((address_space(1))) unsigned int*)ga,
                                             (__attribute__((address_space(3))) unsigned int*)(As[buf] + c * 512),
                                             16, 0, 0);
            const unsigned short* gb = Bbase + (long)row * K + k0;
            __builtin_amdgcn_global_load_lds((const __attribute__((address_space(1))) unsigned int*)gb,
                                             (__attribute__((address_space(3))) unsigned int*)(Bs[buf] + c * 512),
                                             16, 0, 0);
        }
    };

    // read-side swizzle: want global k-segment (lane>>4); stored at slot
    // (lane>>4) ^ ((row>>1)&3), and row bits 1-2 == lane bits 1-2.
    const int rdA = 16 * ((lane >> 4) ^ ((lane >> 1) & 3));  // byte offset in row

    f32x4 acc[4][4] = {};
    const int nt = K / BKg;

    stage(0, 0);
    stage(1, BKg);

    int cur = 0, pf = 2;
    for (int t = 0; t < nt; ++t) {
        if (t + 2 < nt) {
            stage(pf, (t + 2) * BKg);
            asm volatile("s_waitcnt vmcnt(8)" ::: "memory");   // tile t's 4 glls done
        } else if (t + 1 < nt) {
            asm volatile("s_waitcnt vmcnt(4)" ::: "memory");
        } else {
            asm volatile("s_waitcnt vmcnt(0)" ::: "memory");
        }
        __builtin_amdgcn_s_barrier();                          // all waves: tile t resident
        asm volatile("" ::: "memory");

        bf16x8 af[4], bfr[4];
#pragma unroll
        for (int m = 0; m < 4; ++m) {
            const int row = wr * 64 + m * 16 + (lane & 15);
            af[m] = *(const bf16x8*)((const char*)As[cur] + row * 64 + rdA);
        }
#pragma unroll
        for (int n = 0; n < 4; ++n) {
            const int row = wc * 64 + n * 16 + (lane & 15);
            bfr[n] = *(const bf16x8*)((const char*)Bs[cur] + row * 64 + rdA);
        }
        // swapped operands: acc[m][n] holds the TRANSPOSED 16x16 tile:
        // out row = lane&15, out cols = (lane>>4)*4 + r  (r = reg index)
#pragma unroll
        for (int m = 0; m < 4; ++m)
#pragma unroll
            for (int n = 0; n < 4; ++n)
                acc[m][n] = __builtin_amdgcn_mfma_f32_16x16x32_bf16(bfr[n], af[m], acc[m][n], 0, 0, 0);

        asm volatile("" ::: "memory");
        __builtin_amdgcn_s_barrier();                          // reads of buf cur retired
        asm volatile("" ::: "memory");

        cur = (cur == 2) ? 0 : cur + 1;
        pf = (pf == 2) ? 0 : pf + 1;
    }

    const int fr = lane & 15;
    const int fs = lane >> 4;
    if constexpr (MODE == 0) {
        unsigned short* o = (unsigned short*)out;
#pragma unroll
        for (int n = 0; n < 4; ++n) {
            const int col0 = (int)tileN + wc * 64 + n * 16 + fs * 4;   // multiple of 4
            const int h0 = col0 >> 1;                                  // cols (col0,col0+1)->h0, (+2,+3)->h0+1
            const float g0 = __expf(e0[h0]);
            const float g1 = __expf(e0[h0 + 1]);
#pragma unroll
            for (int m = 0; m < 4; ++m) {
                const long grow = tileM + wr * 64 + m * 16 + fr;
                ushort4 pk;
                pk.x = f2bf(acc[m][n][0] * g0);
                pk.y = f2bf(acc[m][n][1] * g0);
                pk.z = f2bf(acc[m][n][2] * g1);
                pk.w = f2bf(acc[m][n][3] * g1);
                *(ushort4*)(o + grow * N + col0) = pk;                 // 8B store, line-coalesced
            }
        }
    } else {
        float* o = (float*)out;
#pragma unroll
        for (int n = 0; n < 4; ++n) {
            const int col0 = (int)tileN + wc * 64 + n * 16 + fs * 4;   // multiple of 4
            const float4 dv = *(const float4*)(e0 + col0);
#pragma unroll
            for (int m = 0; m < 4; ++m) {
                const long grow = tileM + wr * 64 + m * 16 + fr;
                const long idx = grow * N + col0;
                float u0, u1, u2, u3;
                if (e1b) {
                    ushort4 ub = *(const ushort4*)(e1b + idx);
                    u0 = bf2f(ub.x); u1 = bf2f(ub.y); u2 = bf2f(ub.z); u3 = bf2f(ub.w);
                } else {
                    float4 uf = *(const float4*)(e1 + idx);
                    u0 = uf.x; u1 = uf.y; u2 = uf.z; u3 = uf.w;
                }
                float4 st;
                st.x = acc[m][n][0] + dv.x * u0;
                st.y = acc[m][n][1] + dv.y * u1;
                st.z = acc[m][n][2] + dv.z * u2;
                st.w = acc[m][n][3] + dv.w * u3;
                *(float4*)(o + idx) = st;                              // 16B store, line-coalesced
            }
        }
    }
}

// ---------- scan: sums-first, then fused local-scan-from-carry ----------
// thread handles 2 complex h's (ushort4 = 8B loads, 512B/wave coalesced)

// k2s: read-only chunk sums. sums[(b*NC+c)*256+hp] = (re0,im0,re1,im1)
__global__ __launch_bounds__(256) void k2s_sums(const ushort4* __restrict__ xs4,
                                                float4* __restrict__ sums,
                                                const float* __restrict__ nu,
                                                const float* __restrict__ theta) {
    const int gid = blockIdx.x * 256 + threadIdx.x;   // 8*32*256
    const int hp = gid & 255;
    const int c = (gid >> 8) & (NC - 1);
    const int b = gid >> 13;
    float lre0, lim0, lre1, lim1;
    lam_of(nu, theta, 2 * hp, lre0, lim0);
    lam_of(nu, theta, 2 * hp + 1, lre1, lim1);
    long base = ((long)b * T_LEN + (long)c * CL) * 256 + hp;
    float a0r = 0.f, a0i = 0.f, a1r = 0.f, a1i = 0.f;
#pragma unroll 4
    for (int i = 0; i < CL; ++i) {
        ushort4 v = xs4[base + (long)i * 256];
        float u0r = bf2f(v.x), u0i = bf2f(v.y), u1r = bf2f(v.z), u1i = bf2f(v.w);
        float n0r = fmaf(lre0, a0r, fmaf(-lim0, a0i, u0r));
        float n0i = fmaf(lre0, a0i, fmaf(lim0, a0r, u0i));
        float n1r = fmaf(lre1, a1r, fmaf(-lim1, a1i, u1r));
        float n1i = fmaf(lre1, a1i, fmaf(lim1, a1r, u1i));
        a0r = n0r; a0i = n0i; a1r = n1r; a1i = n1i;
    }
    sums[((long)b * NC + c) * 256 + hp] = make_float4(a0r, a0i, a1r, a1i);
}

// k2b: exclusive scan over chunk sums -> carry (same float4-per-hp layout)
__global__ __launch_bounds__(256) void k2b_carry(const float4* __restrict__ sums,
                                                 float4* __restrict__ carry,
                                                 const float* __restrict__ nu,
                                                 const float* __restrict__ theta) {
    const int gid = blockIdx.x * 256 + threadIdx.x;   // 8*256
    const int hp = gid & 255;
    const int b = gid >> 8;
    float lre0, lim0, lre1, lim1;
    lam_of(nu, theta, 2 * hp, lre0, lim0);
    lam_of(nu, theta, 2 * hp + 1, lre1, lim1);
    // lam^CL via 7 complex squarings (CL = 128 = 2^7)
    float p0r = lre0, p0i = lim0, p1r = lre1, p1i = lim1;
#pragma unroll
    for (int i = 0; i < 7; ++i) {
        float t0 = p0r * p0r - p0i * p0i; p0i = 2.f * p0r * p0i; p0r = t0;
        float t1 = p1r * p1r - p1i * p1i; p1i = 2.f * p1r * p1i; p1r = t1;
    }
    float c0r = 0.f, c0i = 0.f, c1r = 0.f, c1i = 0.f;
    for (int c = 0; c < NC; ++c) {
        long idx = ((long)b * NC + c) * 256 + hp;
        carry[idx] = make_float4(c0r, c0i, c1r, c1i);
        float4 s = sums[idx];
        float t0 = fmaf(p0r, c0r, fmaf(-p0i, c0i, s.x));
        c0i = fmaf(p0r, c0i, fmaf(p0i, c0r, s.y));
        c0r = t0;
        float t1 = fmaf(p1r, c1r, fmaf(-p1i, c1i, s.z));
        c1i = fmaf(p1r, c1i, fmaf(p1i, c1r, s.w));
        c1r = t1;
    }
}

// k2ac: fused local scan starting from carry -> final xs (one R+W pass, f32 state throughout)
__global__ __launch_bounds__(256) void k2ac_scan(ushort4* __restrict__ xs4,
                                                 const float4* __restrict__ carry,
                                                 const float* __restrict__ nu,
                                                 const float* __restrict__ theta) {
    const int gid = blockIdx.x * 256 + threadIdx.x;   // 8*32*256
    const int hp = gid & 255;
    const int c = (gid >> 8) & (NC - 1);
    const int b = gid >> 13;
    float lre0, lim0, lre1, lim1;
    lam_of(nu, theta, 2 * hp, lre0, lim0);
    lam_of(nu, theta, 2 * hp + 1, lre1, lim1);
    float4 cr = carry[((long)b * NC + c) * 256 + hp];
    float a0r = cr.x, a0i = cr.y, a1r = cr.z, a1i = cr.w;
    long base = ((long)b * T_LEN + (long)c * CL) * 256 + hp;
#pragma unroll 4
    for (int i = 0; i < CL; ++i) {
        ushort4 v = xs4[base + (long)i * 256];
        float u0r = bf2f(v.x), u0i = bf2f(v.y), u1r = bf2f(v.z), u1i = bf2f(v.w);
        float n0r = fmaf(lre0, a0r, fmaf(-lim0, a0i, u0r));
        float n0i = fmaf(lre0, a0i, fmaf(lim0, a0r, u0i));
        float n1r = fmaf(lre1, a1r, fmaf(-lim1, a1i, u1r));
        float n1i = fmaf(lre1, a1i, fmaf(lim1, a1r, u1i));
        a0r = n0r; a0i = n0i; a1r = n1r; a1i = n1i;
        ushort4 o;
        o.x = f2bf(a0r); o.y = f2bf(a0i); o.z = f2bf(a1r); o.w = f2bf(a1i);
        xs4[base + (long)i * 256] = o;
    }
}

extern "C" void kernel_launch(void* const* d_in, const int* in_sizes, int n_in,
                              void* d_out, int out_size, void* d_ws, size_t ws_size,
                              hipStream_t stream) {
    const float* x         = (const float*)d_in[0];
    const float* Bre       = (const float*)d_in[1];
    const float* Bim       = (const float*)d_in[2];
    const float* Cre       = (const float*)d_in[3];
    const float* Cim       = (const float*)d_in[4];
    const float* Dv        = (const float*)d_in[5];
    const float* nu        = (const float*)d_in[6];
    const float* theta     = (const float*)d_in[7];
    const float* gamma_log = (const float*)d_in[8];
    float* y = (float*)d_out;

    // ws layout:
    //   [0, 64MB)      xs (bf16 interleaved re,im)
    //   [64MB, 66MB)   region A: BT1 (0.5MB) -> sums (1MB) -> CT (0.5MB)
    //   [66MB, 68MB)   region B: carry (1MB)
    //   [68MB, 84MB)   xb (bf16 x) IF ws_size permits, else xb lives in d_out
    const size_t XS_BYTES  = (size_t)ROWS * H_DIM * 4;
    const size_t REG_BYTES = 2u * 1024 * 1024;
    const size_t XB_BYTES  = (size_t)ROWS * N_DIM * 2;
    unsigned short* xs_us = (unsigned short*)d_ws;
    ushort4* xs4   = (ushort4*)d_ws;
    char* regionA  = (char*)d_ws + XS_BYTES;
    char* regionB  = regionA + REG_BYTES;
    unsigned short* BT1 = (unsigned short*)regionA;
    float4*  sums  = (float4*)regionA;
    unsigned short* CT  = (unsigned short*)regionA;
    float4*  carry = (float4*)regionB;

    const bool xb_in_ws = ws_size >= XS_BYTES + 2 * REG_BYTES + XB_BYTES;
    unsigned short* xb = xb_in_ws ? (unsigned short*)(regionB + REG_BYTES)
                                  : (unsigned short*)d_out;

    conv_x<<<ROWS * N_DIM / 4 / 256, 256, 0, stream>>>((const float4*)x, (ushort4*)xb);
    conv_Bt<<<(N_DIM * H_DIM) / 256, 256, 0, stream>>>(Bre, Bim, BT1);

    // K1: xs = gamma * (u @ Bint)   M=32768 N=1024 K=256
    gemm_mfma<0><<<(ROWS / BM) * (1024 / BN), 256, 0, stream>>>(xb, BT1, ROWS, 1024, 256,
                                                                gamma_log, nullptr, nullptr, xs_us);
    // scan: sums-first (sums overwrites BT1 region; K1 complete by stream order)
    k2s_sums<<<(B_SZ * NC * 256) / 256, 256, 0, stream>>>(xs4, sums, nu, theta);
    k2b_carry<<<(B_SZ * 256) / 256, 256, 0, stream>>>(sums, carry, nu, theta);
    k2ac_scan<<<(B_SZ * NC * 256) / 256, 256, 0, stream>>>(xs4, carry, nu, theta);

    // CT overwrites sums region (dead after k2b)
    conv_Ct<<<(H_DIM * N_DIM) / 256, 256, 0, stream>>>(Cre, Cim, CT);

    // K3: y = Re(xs @ C) + D*u      M=32768 N=256 K=1024
    gemm_mfma<1><<<(ROWS / BM) * (256 / BN), 256, 0, stream>>>(xs_us, CT, ROWS, 256, 1024,
                                                               Dv, x, xb_in_ws ? xb : nullptr, y);
}